// Round 1
// baseline (36898.288 us; speedup 1.0000x reference)
//
#include <hip/hip_runtime.h>
#include <cstdint>
#include <cstddef>

#define H   768
#define G3  2304      // 3*H
#define TT  512
#define BS  32
#define RWG 36        // recurrence workgroups; 64 rows of W_hh each

// workspace layout (bytes)
#define WS_CTR 0
#define WS_L   64
#define WS_HG  256          // float hg[2][2304] double-buffered
#define WS_XG  32768        // float xg[16384][2304] = 151 MB

// ---------------- phase 1: lengths + counter init ----------------
__global__ void prep_kernel(const int* __restrict__ mask, int* __restrict__ L,
                            unsigned int* __restrict__ ctr) {
    __shared__ int sbuf[256];
    const int b = blockIdx.x, tid = threadIdx.x;
    int c = 0;
    for (int t = tid; t < TT; t += 256) c += (mask[b * TT + t] != 0) ? 1 : 0;
    sbuf[tid] = c;
    __syncthreads();
    for (int off = 128; off > 0; off >>= 1) {
        if (tid < off) sbuf[tid] += sbuf[tid + off];
        __syncthreads();
    }
    if (tid == 0) {
        int l = sbuf[0];
        if (l < 1) l = 2;          // reference: where(L<1, 2, L)
        L[b] = l;
        if (b == 0) *ctr = 0u;     // ws is re-poisoned before every launch
    }
}

// ---------------- phase 2: xg = emb @ W_ih^T + b_ih ----------------
// A: [16384][768], W: [2304][768], xg: [16384][2304]. Skip tiles with t0 >= L[b].
__global__ __launch_bounds__(256) void xg_gemm(
    const float* __restrict__ A, const float* __restrict__ W,
    const float* __restrict__ bih, const int* __restrict__ L,
    float* __restrict__ xg)
{
    const int mt = blockIdx.x, nt = blockIdx.y;
    const int b  = mt >> 3;
    const int t0 = (mt & 7) << 6;
    if (t0 >= L[b]) return;                       // rows never read by recurrence

    __shared__ __align__(16) float As[16][68];
    __shared__ __align__(16) float Bsh[16][68];

    const int tid = threadIdx.x;
    const int m0 = mt << 6, n0 = nt << 6;
    const int lr = tid >> 2;            // 0..63 tile row for staging loads
    const int lk = (tid & 3) << 2;      // 0,4,8,12
    const int tm = (tid >> 4) << 2;     // 0..60 micro-tile row
    const int tn = (tid & 15) << 2;     // 0..60 micro-tile col

    float c[4][4] = {};
    const float* Ap = A + (size_t)(m0 + lr) * H + lk;
    const float* Wp = W + (size_t)(n0 + lr) * H + lk;

    for (int k0 = 0; k0 < H; k0 += 16) {
        float4 av = *(const float4*)(Ap + k0);
        float4 bv = *(const float4*)(Wp + k0);
        As[lk + 0][lr] = av.x; As[lk + 1][lr] = av.y;
        As[lk + 2][lr] = av.z; As[lk + 3][lr] = av.w;
        Bsh[lk + 0][lr] = bv.x; Bsh[lk + 1][lr] = bv.y;
        Bsh[lk + 2][lr] = bv.z; Bsh[lk + 3][lr] = bv.w;
        __syncthreads();
#pragma unroll
        for (int kk = 0; kk < 16; ++kk) {
            float4 a4 = *(const float4*)&As[kk][tm];
            float4 b4 = *(const float4*)&Bsh[kk][tn];
            c[0][0] = fmaf(a4.x, b4.x, c[0][0]); c[0][1] = fmaf(a4.x, b4.y, c[0][1]);
            c[0][2] = fmaf(a4.x, b4.z, c[0][2]); c[0][3] = fmaf(a4.x, b4.w, c[0][3]);
            c[1][0] = fmaf(a4.y, b4.x, c[1][0]); c[1][1] = fmaf(a4.y, b4.y, c[1][1]);
            c[1][2] = fmaf(a4.y, b4.z, c[1][2]); c[1][3] = fmaf(a4.y, b4.w, c[1][3]);
            c[2][0] = fmaf(a4.z, b4.x, c[2][0]); c[2][1] = fmaf(a4.z, b4.y, c[2][1]);
            c[2][2] = fmaf(a4.z, b4.z, c[2][2]); c[2][3] = fmaf(a4.z, b4.w, c[2][3]);
            c[3][0] = fmaf(a4.w, b4.x, c[3][0]); c[3][1] = fmaf(a4.w, b4.y, c[3][1]);
            c[3][2] = fmaf(a4.w, b4.z, c[3][2]); c[3][3] = fmaf(a4.w, b4.w, c[3][3]);
        }
        __syncthreads();
    }
    const float4 bias = *(const float4*)&bih[n0 + tn];
#pragma unroll
    for (int i = 0; i < 4; ++i) {
        float4 o;
        o.x = c[i][0] + bias.x; o.y = c[i][1] + bias.y;
        o.z = c[i][2] + bias.z; o.w = c[i][3] + bias.w;
        *(float4*)&xg[(size_t)(m0 + tm + i) * G3 + n0 + tn] = o;
    }
}

// ---------------- phase 3: sequential GRU chain ----------------
// 36 WGs, 256 thr. WG owns rows [64*wg, 64*wg+64) of W_hh; wave = K-chunk (192).
// Each thread keeps its 192 f32 weights in VGPRs for the whole kernel.
__global__ __launch_bounds__(256, 1) void gru_kernel(
    const float* __restrict__ Whh, const float* __restrict__ bhh,
    const float* __restrict__ gctx, const float* __restrict__ xg,
    const int* __restrict__ L, unsigned int* ctr,
    float* __restrict__ hg, float* __restrict__ out)
{
    __shared__ __align__(16) float h_lds[H];
    __shared__ float pbuf[256];
    __shared__ int Ls[BS];

    const int tid  = threadIdx.x;
    const int wg   = blockIdx.x;
    const int wave = tid >> 6;            // K-chunk id 0..3
    const int lane = tid & 63;            // row-within-WG
    const int row  = (wg << 6) + lane;    // global gate row 0..2303
    const int kbase = wave * 192;

    // weights -> VGPRs (one-time, ~7 MB total across 36 CUs)
    float w[192];
    const float* wp = Whh + (size_t)row * H + kbase;
#pragma unroll
    for (int i = 0; i < 192; i += 4) {
        float4 v = *(const float4*)(wp + i);
        w[i] = v.x; w[i + 1] = v.y; w[i + 2] = v.z; w[i + 3] = v.w;
    }
    float bias = 0.0f;
    if (tid < 64) bias = bhh[(wg << 6) + tid];
    if (tid < BS) Ls[tid] = L[tid];
    for (int j = tid; j < H; j += 256) h_lds[j] = gctx[j];
    __syncthreads();

    int step = 0;
    for (int b = 0; b < BS; ++b) {
        const int Lb = Ls[b];
        const float* xbase = xg + (size_t)b * TT * G3;
        for (int t = 0; t < Lb; ++t, ++step) {
            // prefetch this step's xg row into registers (independent of h)
            const float* xr = xbase + (size_t)t * G3;
            float xr0 = xr[tid],          xr1 = xr[tid + 256],          xr2 = xr[tid + 512];
            float xz0 = xr[H + tid],      xz1 = xr[H + tid + 256],      xz2 = xr[H + tid + 512];
            float xn0 = xr[2 * H + tid],  xn1 = xr[2 * H + tid + 256],  xn2 = xr[2 * H + tid + 512];

            // partial dot: 192 FMAs against wave-uniform LDS broadcasts
            float4 a = {0.f, 0.f, 0.f, 0.f};
#pragma unroll
            for (int i = 0; i < 192; i += 4) {
                float4 hv = *(const float4*)&h_lds[kbase + i];
                a.x = fmaf(w[i + 0], hv.x, a.x);
                a.y = fmaf(w[i + 1], hv.y, a.y);
                a.z = fmaf(w[i + 2], hv.z, a.z);
                a.w = fmaf(w[i + 3], hv.w, a.w);
            }
            pbuf[tid] = (a.x + a.y) + (a.z + a.w);
            __syncthreads();

            float* hgb = hg + (step & 1) * G3;   // parity double-buffer
            if (tid < 64) {
                float v = ((pbuf[tid] + pbuf[tid + 64]) +
                           (pbuf[tid + 128] + pbuf[tid + 192])) + bias;
                hgb[(wg << 6) + tid] = v;
            }
            __syncthreads();

            // device-scope barrier (monotonic counter, release/acquire)
            if (tid == 0) {
                __threadfence();
                __hip_atomic_fetch_add(ctr, 1u, __ATOMIC_ACQ_REL, __HIP_MEMORY_SCOPE_AGENT);
                const unsigned int target = (unsigned int)(RWG * (step + 1));
                while (__hip_atomic_load(ctr, __ATOMIC_ACQUIRE, __HIP_MEMORY_SCOPE_AGENT) < target) {
                    __builtin_amdgcn_s_sleep(1);
                }
            }
            __syncthreads();

            // redundant gate computation in every WG (no second barrier needed)
            float hr0 = hgb[tid],           hr1 = hgb[tid + 256],           hr2 = hgb[tid + 512];
            float hz0 = hgb[H + tid],       hz1 = hgb[H + tid + 256],       hz2 = hgb[H + tid + 512];
            float hn0 = hgb[2 * H + tid],   hn1 = hgb[2 * H + tid + 256],   hn2 = hgb[2 * H + tid + 512];
            float ho0 = h_lds[tid], ho1 = h_lds[tid + 256], ho2 = h_lds[tid + 512];

            float r0 = 1.f / (1.f + expf(-(xr0 + hr0)));
            float r1 = 1.f / (1.f + expf(-(xr1 + hr1)));
            float r2 = 1.f / (1.f + expf(-(xr2 + hr2)));
            float z0 = 1.f / (1.f + expf(-(xz0 + hz0)));
            float z1 = 1.f / (1.f + expf(-(xz1 + hz1)));
            float z2 = 1.f / (1.f + expf(-(xz2 + hz2)));
            float n0 = tanhf(xn0 + r0 * hn0);
            float n1 = tanhf(xn1 + r1 * hn1);
            float n2 = tanhf(xn2 + r2 * hn2);
            float h0 = (1.f - z0) * n0 + z0 * ho0;
            float h1 = (1.f - z1) * n1 + z1 * ho1;
            float h2 = (1.f - z2) * n2 + z2 * ho2;

            h_lds[tid] = h0; h_lds[tid + 256] = h1; h_lds[tid + 512] = h2;
            if (wg == 0 && t == Lb - 1) {       // outputs[b] = h after L_b steps
                out[b * H + tid] = h0;
                out[b * H + tid + 256] = h1;
                out[b * H + tid + 512] = h2;
            }
            __syncthreads();
        }
    }
    if (wg == 0) {                              // second output: final carry hF
        out[BS * H + tid]       = h_lds[tid];
        out[BS * H + tid + 256] = h_lds[tid + 256];
        out[BS * H + tid + 512] = h_lds[tid + 512];
    }
}

extern "C" void kernel_launch(void* const* d_in, const int* in_sizes, int n_in,
                              void* d_out, int out_size, void* d_ws, size_t ws_size,
                              hipStream_t stream) {
    const float* emb  = (const float*)d_in[0];   // [32][512][768]
    const int*   mask = (const int*)d_in[1];     // [32][512] (jax int64 -> int32, x64 off)
    const float* gctx = (const float*)d_in[2];   // [1][1][768]
    const float* Wih  = (const float*)d_in[3];   // [2304][768]
    const float* Whh  = (const float*)d_in[4];   // [2304][768]
    const float* bih  = (const float*)d_in[5];   // [2304]
    const float* bhh  = (const float*)d_in[6];   // [2304]
    float* out = (float*)d_out;                  // 32*768 + 768 floats

    char* ws = (char*)d_ws;
    unsigned int* ctr = (unsigned int*)(ws + WS_CTR);
    int*   L  = (int*)(ws + WS_L);
    float* hg = (float*)(ws + WS_HG);
    float* xg = (float*)(ws + WS_XG);

    prep_kernel<<<BS, 256, 0, stream>>>(mask, L, ctr);
    xg_gemm<<<dim3(256, 36), 256, 0, stream>>>(emb, Wih, bih, L, xg);
    gru_kernel<<<RWG, 256, 0, stream>>>(Whh, bhh, gctx, xg, L, ctr, hg, out);
}